// Round 2
// baseline (964.360 us; speedup 1.0000x reference)
//
#include <hip/hip_runtime.h>
#include <hip/hip_bf16.h>
#include <math.h>

#define D_MODEL 1024
#define D_HIDDEN 4096
#define N_EXP 8
#define N_TOK 4096

typedef __attribute__((ext_vector_type(8))) __bf16 bf16x8_t;
typedef __attribute__((ext_vector_type(4))) float f32x4_t;

// ---- workspace layout (bytes) ----
// counts : 8 ints                     @ 0
// bucket : 8*4096 ints (128 KiB)     @ 256
// xb     : 4096*1024 bf16 (8 MiB)    @ 256 KiB
// h      : 4096*4096 bf16 (32 MiB)   @ 256 KiB + 8 MiB
#define WS_BUCKET_OFF 256
#define WS_XB_OFF     (1u << 18)
#define WS_H_OFF      ((1u << 18) + (8u << 20))

__device__ __forceinline__ void gload16(const void* g, void* l) {
    __builtin_amdgcn_global_load_lds(
        (__attribute__((address_space(1))) void*)(g),
        (__attribute__((address_space(3))) void*)(l),
        16, 0, 0);
}

__global__ __launch_bounds__(64) void init_counts(int* counts) {
    if (threadIdx.x < N_EXP) counts[threadIdx.x] = 0;
}

// Router: one wave per token. fp64 accumulation for logits (argmax robustness),
// also converts x row to bf16 (coalesced 2B stores).
__global__ __launch_bounds__(256) void router_kernel(
    const float* __restrict__ x, const float* __restrict__ Wg,
    const float* __restrict__ bg, int* __restrict__ counts,
    int* __restrict__ bucket, __hip_bfloat16* __restrict__ xb)
{
    const int wid  = threadIdx.x >> 6;
    const int lane = threadIdx.x & 63;
    const int t    = blockIdx.x * 4 + wid;
    const float* xr = x + (size_t)t * D_MODEL;

    double acc[N_EXP];
#pragma unroll
    for (int e = 0; e < N_EXP; ++e) acc[e] = 0.0;

#pragma unroll
    for (int j = 0; j < D_MODEL / 64; ++j) {
        const int d = j * 64 + lane;
        const float xv = xr[d];
        xb[(size_t)t * D_MODEL + d] = __float2bfloat16(xv);
        const float4* wr = (const float4*)(Wg + (size_t)d * N_EXP);
        const float4 w0 = wr[0], w1 = wr[1];
        const double xd = (double)xv;
        acc[0] += xd * (double)w0.x; acc[1] += xd * (double)w0.y;
        acc[2] += xd * (double)w0.z; acc[3] += xd * (double)w0.w;
        acc[4] += xd * (double)w1.x; acc[5] += xd * (double)w1.y;
        acc[6] += xd * (double)w1.z; acc[7] += xd * (double)w1.w;
    }
#pragma unroll
    for (int e = 0; e < N_EXP; ++e) {
        double v = acc[e];
#pragma unroll
        for (int off = 32; off >= 1; off >>= 1) v += __shfl_xor(v, off, 64);
        acc[e] = v + (double)bg[e];
    }
    if (lane == 0) {
        int best = 0; double bv = acc[0];
#pragma unroll
        for (int e = 1; e < N_EXP; ++e)
            if (acc[e] > bv) { bv = acc[e]; best = e; }   // strict > : first max wins (np argmax)
        const int pos = atomicAdd(&counts[best], 1);
        bucket[best * N_TOK + pos] = t;
    }
}

// Grouped GEMM over one expert's token bucket.
// A: [N_TOK][K_TOT] bf16 (gathered rows by token id), staged via global_load_lds.
// W: [E][K_TOT][N_TOT] fp32, reg-staged + converted to bf16, transposed into Bs[n][k].
// Tile 128x128x64, 4 waves; each wave owns a 64x64 sub-tile: 4x4 fragments of
// 16x16x32 MFMA x 2 k-slices = 32 MFMA per K-step vs 16 ds_read_b128 (2:1).
// All LDS rows are 128B = 8 x 16B slots, swizzled: phys_slot = slot ^ (row&7).
template<int K_TOT, int N_TOT, bool IS_FFN1>
__global__ __launch_bounds__(256, 2) void ffn_gemm(
    const __hip_bfloat16* __restrict__ A,
    const float* __restrict__ W,
    const float* __restrict__ bias,
    const int* __restrict__ counts,
    const int* __restrict__ bucket,
    __hip_bfloat16* __restrict__ hout,
    float* __restrict__ yout)
{
    const int e   = blockIdx.z;
    const int cnt = counts[e];
    const int m0  = blockIdx.y * 128;
    if (m0 >= cnt) return;
    const int n0   = blockIdx.x * 128;
    const int tid  = threadIdx.x;
    const int lane = tid & 63;
    const int wid  = tid >> 6;
    const int wm   = wid >> 1, wn = wid & 1;

    __shared__ __hip_bfloat16 As[128 * 64];
    __shared__ __hip_bfloat16 Bs[128 * 64];
    __shared__ int s_tok[128];

    if (tid < 128) {
        int idx = m0 + tid;
        if (idx >= cnt) idx = cnt - 1;       // clamp: pad rows read a valid token
        s_tok[tid] = bucket[e * N_TOK + idx];
    }
    __syncthreads();

    // ---- A staging setup: 4 global_load_lds(16B) per wave ----
    // instr i covers rows wid*32 + i*8 .. +7 (8 lanes per row, 16B each).
    // Global source pre-swizzled: phys slot (lane&7) holds logical oct (lane&7)^(row&7).
    const __hip_bfloat16* gA[4];
    char* lA[4];
#pragma unroll
    for (int i = 0; i < 4; ++i) {
        const int r = wid * 32 + i * 8 + (lane >> 3);
        const int tok = s_tok[r];
        gA[i] = A + (size_t)tok * K_TOT + (((lane & 7) ^ (r & 7)) << 3);
        lA[i] = (char*)As + (size_t)(wid * 32 + i * 8) * 128;  // wave-uniform base
    }

    // ---- B staging mapping: thread = (k-oct bq, n-quad bgq) ----
    const int bgq = tid & 31;       // n = bgq*4 .. +3
    const int bq  = tid >> 5;       // k = bq*8 .. +7
    const float* wb = W + (size_t)e * K_TOT * N_TOT + (size_t)(bq * 8) * N_TOT + n0 + bgq * 4;

    f32x4_t acc[4][4];
#pragma unroll
    for (int f = 0; f < 4; ++f)
#pragma unroll
        for (int g = 0; g < 4; ++g) acc[f][g] = (f32x4_t){0.f, 0.f, 0.f, 0.f};

    for (int k0 = 0; k0 < K_TOT; k0 += 64) {
        // ---- stage A (async direct-to-LDS) ----
#pragma unroll
        for (int i = 0; i < 4; ++i) gload16(gA[i] + k0, lA[i]);

        // ---- stage B: 8 float4 rows -> bf16 -> 4x ds_write_b128 (transposed) ----
        const float* wk = wb + (size_t)k0 * N_TOT;
        float4 v[8];
#pragma unroll
        for (int j = 0; j < 8; ++j) v[j] = *(const float4*)(wk + (size_t)j * N_TOT);
#pragma unroll
        for (int i = 0; i < 4; ++i) {
            const int ii = (i + bgq) & 3;        // rotate write order: spreads n&7 over
            const int n = bgq * 4 + ii;          // all 8 swizzle slots per instruction
            union { __hip_bfloat16 hh[8]; uint4 u; } pk;
#pragma unroll
            for (int j = 0; j < 8; ++j) pk.hh[j] = __float2bfloat16(((const float*)&v[j])[ii]);
            *(uint4*)((char*)Bs + n * 128 + ((bq ^ (n & 7)) << 4)) = pk.u;
        }
        __syncthreads();   // drains vmcnt (global_load_lds) + lgkm (ds_write)

        // ---- fragments + MFMA: 32 per wave per K-step ----
#pragma unroll
        for (int kk = 0; kk < 2; ++kk) {
            uint4 af[4], bf[4];
            const int ko = kk * 4 + (lane >> 4);
#pragma unroll
            for (int f = 0; f < 4; ++f) {
                const int r = wm * 64 + f * 16 + (lane & 15);
                af[f] = *(const uint4*)((const char*)As + r * 128 + ((ko ^ (r & 7)) << 4));
            }
#pragma unroll
            for (int g = 0; g < 4; ++g) {
                const int n = wn * 64 + g * 16 + (lane & 15);
                bf[g] = *(const uint4*)((const char*)Bs + n * 128 + ((ko ^ (n & 7)) << 4));
            }
#pragma unroll
            for (int f = 0; f < 4; ++f)
#pragma unroll
                for (int g = 0; g < 4; ++g)
                    acc[f][g] = __builtin_amdgcn_mfma_f32_16x16x32_bf16(
                        __builtin_bit_cast(bf16x8_t, af[f]),
                        __builtin_bit_cast(bf16x8_t, bf[g]),
                        acc[f][g], 0, 0, 0);
        }
        __syncthreads();   // protect LDS from next iteration's staging
    }

    // ---- epilogue: C/D layout col=lane&15, row=(lane>>4)*4+j ----
#pragma unroll
    for (int f = 0; f < 4; ++f) {
#pragma unroll
        for (int j = 0; j < 4; ++j) {
            const int rl = wm * 64 + f * 16 + (lane >> 4) * 4 + j;
            const bool ok = (m0 + rl) < cnt;
            const int tok = s_tok[rl];
#pragma unroll
            for (int g = 0; g < 4; ++g) {
                const int col = n0 + wn * 64 + g * 16 + (lane & 15);
                float v = acc[f][g][j] + bias[e * N_TOT + col];
                if (IS_FFN1) {
                    v = 0.5f * v * (1.0f + erff(v * 0.70710678118654752f));  // exact gelu
                    if (ok) hout[(size_t)tok * N_TOT + col] = __float2bfloat16(v);
                } else {
                    if (ok) yout[(size_t)tok * N_TOT + col] = v;
                }
            }
        }
    }
}

extern "C" void kernel_launch(void* const* d_in, const int* in_sizes, int n_in,
                              void* d_out, int out_size, void* d_ws, size_t ws_size,
                              hipStream_t stream) {
    const float* x  = (const float*)d_in[0];
    const float* Wg = (const float*)d_in[1];
    const float* bg = (const float*)d_in[2];
    const float* W1 = (const float*)d_in[3];
    const float* b1 = (const float*)d_in[4];
    const float* W2 = (const float*)d_in[5];
    const float* b2 = (const float*)d_in[6];
    float* out = (float*)d_out;

    char* ws = (char*)d_ws;
    int* counts = (int*)(ws);
    int* bucket = (int*)(ws + WS_BUCKET_OFF);
    __hip_bfloat16* xb = (__hip_bfloat16*)(ws + WS_XB_OFF);
    __hip_bfloat16* h  = (__hip_bfloat16*)(ws + WS_H_OFF);

    init_counts<<<dim3(1), dim3(64), 0, stream>>>(counts);
    router_kernel<<<dim3(N_TOK / 4), dim3(256), 0, stream>>>(x, Wg, bg, counts, bucket, xb);
    // FFN1: h[tok] = gelu(x[tok] @ W1[e] + b1[e]);  M<=4096 per expert, N=4096, K=1024
    ffn_gemm<D_MODEL, D_HIDDEN, true><<<dim3(D_HIDDEN / 128, N_TOK / 128, N_EXP), dim3(256), 0, stream>>>(
        xb, W1, b1, counts, bucket, h, nullptr);
    // FFN2: out[tok] = h[tok] @ W2[e] + b2[e];  N=1024, K=4096
    ffn_gemm<D_HIDDEN, D_MODEL, false><<<dim3(D_MODEL / 128, N_TOK / 128, N_EXP), dim3(256), 0, stream>>>(
        h, W2, b2, counts, bucket, nullptr, out);
}

// Round 3
// 399.083 us; speedup vs baseline: 2.4164x; 2.4164x over previous
//
#include <hip/hip_runtime.h>
#include <hip/hip_bf16.h>
#include <math.h>

#define D_MODEL 1024
#define D_HIDDEN 4096
#define N_EXP 8
#define N_TOK 4096

typedef __attribute__((ext_vector_type(8))) __bf16 bf16x8_t;
typedef __attribute__((ext_vector_type(4))) float f32x4_t;

// ---- workspace layout (bytes) ----
// counts : 8 ints                     @ 0
// bucket : 8*4096 ints (128 KiB)     @ 256
// xb     : 4096*1024 bf16 (8 MiB)    @ 256 KiB
// h      : 4096*4096 bf16 (32 MiB)   @ 256 KiB + 8 MiB
#define WS_BUCKET_OFF 256
#define WS_XB_OFF     (1u << 18)
#define WS_H_OFF      ((1u << 18) + (8u << 20))

__device__ __forceinline__ void gload16(const void* g, void* l) {
    __builtin_amdgcn_global_load_lds(
        (__attribute__((address_space(1))) void*)(g),
        (__attribute__((address_space(3))) void*)(l),
        16, 0, 0);
}

__global__ __launch_bounds__(64) void init_counts(int* counts) {
    if (threadIdx.x < N_EXP) counts[threadIdx.x] = 0;
}

// Router: one wave per token. fp64 accumulation for logits (argmax robustness),
// also converts x row to bf16 (coalesced 2B stores).
__global__ __launch_bounds__(256) void router_kernel(
    const float* __restrict__ x, const float* __restrict__ Wg,
    const float* __restrict__ bg, int* __restrict__ counts,
    int* __restrict__ bucket, __hip_bfloat16* __restrict__ xb)
{
    const int wid  = threadIdx.x >> 6;
    const int lane = threadIdx.x & 63;
    const int t    = blockIdx.x * 4 + wid;
    const float* xr = x + (size_t)t * D_MODEL;

    double acc[N_EXP];
#pragma unroll
    for (int e = 0; e < N_EXP; ++e) acc[e] = 0.0;

#pragma unroll
    for (int j = 0; j < D_MODEL / 64; ++j) {
        const int d = j * 64 + lane;
        const float xv = xr[d];
        xb[(size_t)t * D_MODEL + d] = __float2bfloat16(xv);
        const float4* wr = (const float4*)(Wg + (size_t)d * N_EXP);
        const float4 w0 = wr[0], w1 = wr[1];
        const double xd = (double)xv;
        acc[0] += xd * (double)w0.x; acc[1] += xd * (double)w0.y;
        acc[2] += xd * (double)w0.z; acc[3] += xd * (double)w0.w;
        acc[4] += xd * (double)w1.x; acc[5] += xd * (double)w1.y;
        acc[6] += xd * (double)w1.z; acc[7] += xd * (double)w1.w;
    }
#pragma unroll
    for (int e = 0; e < N_EXP; ++e) {
        double v = acc[e];
#pragma unroll
        for (int off = 32; off >= 1; off >>= 1) v += __shfl_xor(v, off, 64);
        acc[e] = v + (double)bg[e];
    }
    if (lane == 0) {
        int best = 0; double bv = acc[0];
#pragma unroll
        for (int e = 1; e < N_EXP; ++e)
            if (acc[e] > bv) { bv = acc[e]; best = e; }   // strict > : first max wins (np argmax)
        const int pos = atomicAdd(&counts[best], 1);
        bucket[best * N_TOK + pos] = t;
    }
}

// Grouped GEMM over one expert's token bucket.
// A: [N_TOK][K_TOT] bf16 (gathered rows by token id), staged via global_load_lds.
// W: [E][K_TOT][N_TOT] fp32, reg-staged + converted to bf16, transposed into Bs[n][k].
// Tile 128x128x64, 4 waves; each wave owns a 64x64 sub-tile: 4x4 fragments of
// 16x16x32 MFMA x 2 k-slices = 32 MFMA per K-step vs 16 ds_read_b128 (2:1).
// All LDS rows are 128B = 8 x 16B slots, swizzled: phys_slot = slot ^ (row&7).
// B-staging thread map: ko = lane&7 (k-oct), nq = wid*8 + (lane>>3) (n-quad).
//  -> within one ds_write_b128 the wave's ko spans 0..7, so XOR-swizzled slots
//     cover all 32 banks evenly (conflict-free) AND component extraction is
//     compile-time (no scratch; rule #20).
template<int K_TOT, int N_TOT, bool IS_FFN1>
__global__ __launch_bounds__(256, 2) void ffn_gemm(
    const __hip_bfloat16* __restrict__ A,
    const float* __restrict__ W,
    const float* __restrict__ bias,
    const int* __restrict__ counts,
    const int* __restrict__ bucket,
    __hip_bfloat16* __restrict__ hout,
    float* __restrict__ yout)
{
    const int e   = blockIdx.z;
    const int cnt = counts[e];
    const int m0  = blockIdx.y * 128;
    if (m0 >= cnt) return;
    const int n0   = blockIdx.x * 128;
    const int tid  = threadIdx.x;
    const int lane = tid & 63;
    const int wid  = tid >> 6;
    const int wm   = wid >> 1, wn = wid & 1;

    __shared__ __hip_bfloat16 As[128 * 64];
    __shared__ __hip_bfloat16 Bs[128 * 64];
    __shared__ int s_tok[128];

    if (tid < 128) {
        int idx = m0 + tid;
        if (idx >= cnt) idx = cnt - 1;       // clamp: pad rows read a valid token
        s_tok[tid] = bucket[e * N_TOK + idx];
    }
    __syncthreads();

    // ---- A staging setup: 4 global_load_lds(16B) per wave ----
    // instr i covers rows wid*32 + i*8 .. +7 (8 lanes per row, 16B each).
    // Global source pre-swizzled: phys slot (lane&7) holds logical oct (lane&7)^(row&7).
    const __hip_bfloat16* gA[4];
    char* lA[4];
#pragma unroll
    for (int i = 0; i < 4; ++i) {
        const int r = wid * 32 + i * 8 + (lane >> 3);
        const int tok = s_tok[r];
        gA[i] = A + (size_t)tok * K_TOT + (((lane & 7) ^ (r & 7)) << 3);
        lA[i] = (char*)As + (size_t)(wid * 32 + i * 8) * 128;  // wave-uniform base
    }

    // ---- B staging mapping: thread = (k-oct ko_t, n-quad nq) ----
    const int ko_t = lane & 7;             // k rows ko_t*8 .. +7
    const int nq   = wid * 8 + (lane >> 3); // cols nq*4 .. +3
    const float* wb = W + (size_t)e * K_TOT * N_TOT + (size_t)(ko_t * 8) * N_TOT + n0 + nq * 4;

    f32x4_t acc[4][4];
#pragma unroll
    for (int f = 0; f < 4; ++f)
#pragma unroll
        for (int g = 0; g < 4; ++g) acc[f][g] = (f32x4_t){0.f, 0.f, 0.f, 0.f};

    for (int k0 = 0; k0 < K_TOT; k0 += 64) {
        // ---- stage A (async direct-to-LDS) ----
#pragma unroll
        for (int i = 0; i < 4; ++i) gload16(gA[i] + k0, lA[i]);

        // ---- stage B: 8 float4 rows -> bf16 -> 4x ds_write_b128 (transposed) ----
        const float* wk = wb + (size_t)k0 * N_TOT;
        float4 v[8];
#pragma unroll
        for (int j = 0; j < 8; ++j) v[j] = *(const float4*)(wk + (size_t)j * N_TOT);
#pragma unroll
        for (int i = 0; i < 4; ++i) {           // i compile-time: no scratch
            const int n = nq * 4 + i;
            union { __hip_bfloat16 hh[8]; uint4 u; } pk;
#pragma unroll
            for (int j = 0; j < 8; ++j) pk.hh[j] = __float2bfloat16(((const float*)&v[j])[i]);
            *(uint4*)((char*)Bs + n * 128 + ((ko_t ^ (n & 7)) << 4)) = pk.u;
        }
        __syncthreads();   // drains vmcnt (global_load_lds) + lgkm (ds_write)

        // ---- fragments + MFMA: 32 per wave per K-step ----
#pragma unroll
        for (int kk = 0; kk < 2; ++kk) {
            uint4 af[4], bf[4];
            const int ko = kk * 4 + (lane >> 4);
#pragma unroll
            for (int f = 0; f < 4; ++f) {
                const int r = wm * 64 + f * 16 + (lane & 15);
                af[f] = *(const uint4*)((const char*)As + r * 128 + ((ko ^ (r & 7)) << 4));
            }
#pragma unroll
            for (int g = 0; g < 4; ++g) {
                const int n = wn * 64 + g * 16 + (lane & 15);
                bf[g] = *(const uint4*)((const char*)Bs + n * 128 + ((ko ^ (n & 7)) << 4));
            }
#pragma unroll
            for (int f = 0; f < 4; ++f)
#pragma unroll
                for (int g = 0; g < 4; ++g)
                    acc[f][g] = __builtin_amdgcn_mfma_f32_16x16x32_bf16(
                        __builtin_bit_cast(bf16x8_t, af[f]),
                        __builtin_bit_cast(bf16x8_t, bf[g]),
                        acc[f][g], 0, 0, 0);
        }
        __syncthreads();   // protect LDS from next iteration's staging
    }

    // ---- epilogue: C/D layout col=lane&15, row=(lane>>4)*4+j ----
#pragma unroll
    for (int f = 0; f < 4; ++f) {
#pragma unroll
        for (int j = 0; j < 4; ++j) {
            const int rl = wm * 64 + f * 16 + (lane >> 4) * 4 + j;
            const bool ok = (m0 + rl) < cnt;
            const int tok = s_tok[rl];
#pragma unroll
            for (int g = 0; g < 4; ++g) {
                const int col = n0 + wn * 64 + g * 16 + (lane & 15);
                float v = acc[f][g][j] + bias[e * N_TOT + col];
                if (IS_FFN1) {
                    v = 0.5f * v * (1.0f + erff(v * 0.70710678118654752f));  // exact gelu
                    if (ok) hout[(size_t)tok * N_TOT + col] = __float2bfloat16(v);
                } else {
                    if (ok) yout[(size_t)tok * N_TOT + col] = v;
                }
            }
        }
    }
}

extern "C" void kernel_launch(void* const* d_in, const int* in_sizes, int n_in,
                              void* d_out, int out_size, void* d_ws, size_t ws_size,
                              hipStream_t stream) {
    const float* x  = (const float*)d_in[0];
    const float* Wg = (const float*)d_in[1];
    const float* bg = (const float*)d_in[2];
    const float* W1 = (const float*)d_in[3];
    const float* b1 = (const float*)d_in[4];
    const float* W2 = (const float*)d_in[5];
    const float* b2 = (const float*)d_in[6];
    float* out = (float*)d_out;

    char* ws = (char*)d_ws;
    int* counts = (int*)(ws);
    int* bucket = (int*)(ws + WS_BUCKET_OFF);
    __hip_bfloat16* xb = (__hip_bfloat16*)(ws + WS_XB_OFF);
    __hip_bfloat16* h  = (__hip_bfloat16*)(ws + WS_H_OFF);

    init_counts<<<dim3(1), dim3(64), 0, stream>>>(counts);
    router_kernel<<<dim3(N_TOK / 4), dim3(256), 0, stream>>>(x, Wg, bg, counts, bucket, xb);
    // FFN1: h[tok] = gelu(x[tok] @ W1[e] + b1[e]);  M<=4096 per expert, N=4096, K=1024
    ffn_gemm<D_MODEL, D_HIDDEN, true><<<dim3(D_HIDDEN / 128, N_TOK / 128, N_EXP), dim3(256), 0, stream>>>(
        xb, W1, b1, counts, bucket, h, nullptr);
    // FFN2: out[tok] = h[tok] @ W2[e] + b2[e];  N=1024, K=4096
    ffn_gemm<D_HIDDEN, D_MODEL, false><<<dim3(D_MODEL / 128, N_TOK / 128, N_EXP), dim3(256), 0, stream>>>(
        h, W2, b2, counts, bucket, nullptr, out);
}

// Round 4
// 315.603 us; speedup vs baseline: 3.0556x; 1.2645x over previous
//
#include <hip/hip_runtime.h>
#include <hip/hip_bf16.h>
#include <math.h>

#define D_MODEL 1024
#define D_HIDDEN 4096
#define N_EXP 8
#define N_TOK 4096

typedef __attribute__((ext_vector_type(8))) __bf16 bf16x8_t;
typedef __attribute__((ext_vector_type(4))) float f32x4_t;

// ---- workspace layout (bytes) ----
// counts : 8 ints                      @ 0
// bucket : 8*4096 ints (128 KiB)       @ 256
// xb     : 4096*1024 bf16 (8 MiB)      @ 256 KiB
// h      : 4096*4096 bf16 (32 MiB)     @ 256 KiB + 8 MiB
// W1b    : 8*4096*1024 bf16 (64 MiB)   @ 256 KiB + 40 MiB   [n][k] transposed
// W2b    : 8*1024*4096 bf16 (64 MiB)   @ 256 KiB + 104 MiB  [n][k] transposed
#define WS_BUCKET_OFF 256
#define WS_XB_OFF     ((size_t)1 << 18)
#define WS_H_OFF      (((size_t)1 << 18) + ((size_t)8 << 20))
#define WS_W1B_OFF    (((size_t)1 << 18) + ((size_t)40 << 20))
#define WS_W2B_OFF    (((size_t)1 << 18) + ((size_t)104 << 20))
#define WS_NEED       (((size_t)1 << 18) + ((size_t)168 << 20))

__device__ __forceinline__ void gload16(const void* g, void* l) {
    __builtin_amdgcn_global_load_lds(
        (__attribute__((address_space(1))) void*)(g),
        (__attribute__((address_space(3))) void*)(l),
        16, 0, 0);
}

__global__ __launch_bounds__(64) void init_counts(int* counts) {
    if (threadIdx.x < N_EXP) counts[threadIdx.x] = 0;
}

// Router: one wave per token. fp64 accumulation for logits (argmax robustness),
// also converts x row to bf16 (coalesced 2B stores).
__global__ __launch_bounds__(256) void router_kernel(
    const float* __restrict__ x, const float* __restrict__ Wg,
    const float* __restrict__ bg, int* __restrict__ counts,
    int* __restrict__ bucket, __hip_bfloat16* __restrict__ xb)
{
    const int wid  = threadIdx.x >> 6;
    const int lane = threadIdx.x & 63;
    const int t    = blockIdx.x * 4 + wid;
    const float* xr = x + (size_t)t * D_MODEL;

    double acc[N_EXP];
#pragma unroll
    for (int e = 0; e < N_EXP; ++e) acc[e] = 0.0;

#pragma unroll
    for (int j = 0; j < D_MODEL / 64; ++j) {
        const int d = j * 64 + lane;
        const float xv = xr[d];
        xb[(size_t)t * D_MODEL + d] = __float2bfloat16(xv);
        const float4* wr = (const float4*)(Wg + (size_t)d * N_EXP);
        const float4 w0 = wr[0], w1 = wr[1];
        const double xd = (double)xv;
        acc[0] += xd * (double)w0.x; acc[1] += xd * (double)w0.y;
        acc[2] += xd * (double)w0.z; acc[3] += xd * (double)w0.w;
        acc[4] += xd * (double)w1.x; acc[5] += xd * (double)w1.y;
        acc[6] += xd * (double)w1.z; acc[7] += xd * (double)w1.w;
    }
#pragma unroll
    for (int e = 0; e < N_EXP; ++e) {
        double v = acc[e];
#pragma unroll
        for (int off = 32; off >= 1; off >>= 1) v += __shfl_xor(v, off, 64);
        acc[e] = v + (double)bg[e];
    }
    if (lane == 0) {
        int best = 0; double bv = acc[0];
#pragma unroll
        for (int e = 1; e < N_EXP; ++e)
            if (acc[e] > bv) { bv = acc[e]; best = e; }   // strict > : first max wins (np argmax)
        const int pos = atomicAdd(&counts[best], 1);
        bucket[best * N_TOK + pos] = t;
    }
}

// W fp32 [e][k][n]  ->  Wb bf16 [e][n][k], via LDS-tiled 64x64 transpose.
// Read: wave w, lane nl: 16 scalar fp32 (k = w*16+r*4+s, n = nl) — 256B/row coalesced.
// LDS tile [n=64][k=64] bf16, row stride 68 halves (136B, 8B aligned, pad kills
// power-of-2 bank stride). Write b64 (4 consecutive k packed). Readout: 4x b64
// per thread -> 2x dwordx4 global store, 128B segments per n-row.
template<int KT, int NT>
__global__ __launch_bounds__(256) void convert_w(
    const float* __restrict__ W, __hip_bfloat16* __restrict__ Wb)
{
    const int e  = blockIdx.z;
    const int k0 = blockIdx.y * 64;
    const int n0 = blockIdx.x * 64;
    const int tid = threadIdx.x;
    const int w   = tid >> 6;
    const int lane = tid & 63;

    __shared__ __hip_bfloat16 Lt[64 * 68];

    const float* src = W + (size_t)e * KT * NT + (size_t)k0 * NT + n0 + lane;
#pragma unroll
    for (int r = 0; r < 4; ++r) {
        const int kk = w * 16 + r * 4;
        union { __hip_bfloat16 hh[4]; unsigned long long u; } pk;
#pragma unroll
        for (int s = 0; s < 4; ++s)
            pk.hh[s] = __float2bfloat16(src[(size_t)(kk + s) * NT]);
        *(unsigned long long*)((char*)Lt + (size_t)lane * 136 + kk * 2) = pk.u;
    }
    __syncthreads();

    const int nr   = w * 16 + (lane >> 2);
    const int half = lane & 3;
    const char* rp = (const char*)Lt + (size_t)nr * 136 + half * 32;
    const uint2 a0 = *(const uint2*)(rp);
    const uint2 a1 = *(const uint2*)(rp + 8);
    const uint2 b0 = *(const uint2*)(rp + 16);
    const uint2 b1 = *(const uint2*)(rp + 24);
    __hip_bfloat16* op = Wb + (size_t)e * NT * KT + (size_t)(n0 + nr) * KT + k0 + half * 16;
    *(uint4*)op       = make_uint4(a0.x, a0.y, a1.x, a1.y);
    *(uint4*)(op + 8) = make_uint4(b0.x, b0.y, b1.x, b1.y);
}

// ===================== bf16-W grouped GEMM (m97 structure) =====================
// A: [N_TOK][K_TOT] bf16 gathered rows; Wb: [E][N_TOT][K_TOT] bf16.
// Both staged via global_load_lds with XOR-swizzled (pre-swizzled-source) LDS.
// Tile 128 x BN x 64, 4 waves; wave tile 64 x BN/2.
template<int K_TOT, int N_TOT, int BN, bool IS_FFN1>
__global__ __launch_bounds__(256, 2) void ffn_gemm_bf16(
    const __hip_bfloat16* __restrict__ A,
    const __hip_bfloat16* __restrict__ Wb,
    const float* __restrict__ bias,
    const int* __restrict__ counts,
    const int* __restrict__ bucket,
    __hip_bfloat16* __restrict__ hout,
    float* __restrict__ yout)
{
    constexpr int NG  = BN / 32;   // n-fragments per wave
    constexpr int NBI = BN / 32;   // B gload16 instrs per wave

    const int e   = blockIdx.z;
    const int cnt = counts[e];
    const int m0  = blockIdx.y * 128;
    if (m0 >= cnt) return;
    const int n0   = blockIdx.x * BN;
    const int tid  = threadIdx.x;
    const int lane = tid & 63;
    const int wid  = tid >> 6;
    const int wm   = wid >> 1, wn = wid & 1;

    __shared__ __hip_bfloat16 As[128 * 64];
    __shared__ __hip_bfloat16 Bs[BN * 64];
    __shared__ int s_tok[128];

    if (tid < 128) {
        int idx = m0 + tid;
        if (idx >= cnt) idx = cnt - 1;
        s_tok[tid] = bucket[e * N_TOK + idx];
    }
    __syncthreads();

    const __hip_bfloat16* gA[4]; char* lA[4];
#pragma unroll
    for (int i = 0; i < 4; ++i) {
        const int r = wid * 32 + i * 8 + (lane >> 3);
        gA[i] = A + (size_t)s_tok[r] * K_TOT + (((lane & 7) ^ (r & 7)) << 3);
        lA[i] = (char*)As + (size_t)(wid * 32 + i * 8) * 128;
    }
    const __hip_bfloat16* gB[NBI]; char* lB[NBI];
    const __hip_bfloat16* wbase = Wb + (size_t)e * N_TOT * K_TOT;
#pragma unroll
    for (int i = 0; i < NBI; ++i) {
        const int r = wid * (BN / 4) + i * 8 + (lane >> 3);
        gB[i] = wbase + (size_t)(n0 + r) * K_TOT + (((lane & 7) ^ (r & 7)) << 3);
        lB[i] = (char*)Bs + (size_t)(wid * (BN / 4) + i * 8) * 128;
    }

    f32x4_t acc[4][NG];
#pragma unroll
    for (int f = 0; f < 4; ++f)
#pragma unroll
        for (int g = 0; g < NG; ++g) acc[f][g] = (f32x4_t){0.f, 0.f, 0.f, 0.f};

    for (int k0 = 0; k0 < K_TOT; k0 += 64) {
#pragma unroll
        for (int i = 0; i < 4; ++i) gload16(gA[i] + k0, lA[i]);
#pragma unroll
        for (int i = 0; i < NBI; ++i) gload16(gB[i] + k0, lB[i]);
        __syncthreads();   // drains vmcnt (global_load_lds)

#pragma unroll
        for (int kk = 0; kk < 2; ++kk) {
            uint4 af[4], bf[NG];
            const int ko = kk * 4 + (lane >> 4);
#pragma unroll
            for (int f = 0; f < 4; ++f) {
                const int r = wm * 64 + f * 16 + (lane & 15);
                af[f] = *(const uint4*)((const char*)As + r * 128 + ((ko ^ (r & 7)) << 4));
            }
#pragma unroll
            for (int g = 0; g < NG; ++g) {
                const int n = wn * (BN / 2) + g * 16 + (lane & 15);
                bf[g] = *(const uint4*)((const char*)Bs + n * 128 + ((ko ^ (n & 7)) << 4));
            }
#pragma unroll
            for (int f = 0; f < 4; ++f)
#pragma unroll
                for (int g = 0; g < NG; ++g)
                    acc[f][g] = __builtin_amdgcn_mfma_f32_16x16x32_bf16(
                        __builtin_bit_cast(bf16x8_t, af[f]),
                        __builtin_bit_cast(bf16x8_t, bf[g]),
                        acc[f][g], 0, 0, 0);
        }
        __syncthreads();
    }

#pragma unroll
    for (int f = 0; f < 4; ++f) {
#pragma unroll
        for (int j = 0; j < 4; ++j) {
            const int rl = wm * 64 + f * 16 + (lane >> 4) * 4 + j;
            const bool ok = (m0 + rl) < cnt;
            const int tok = s_tok[rl];
#pragma unroll
            for (int g = 0; g < NG; ++g) {
                const int col = n0 + wn * (BN / 2) + g * 16 + (lane & 15);
                float v = acc[f][g][j] + bias[e * N_TOT + col];
                if (IS_FFN1) {
                    v = 0.5f * v * (1.0f + erff(v * 0.70710678118654752f));
                    if (ok) hout[(size_t)tok * N_TOT + col] = __float2bfloat16(v);
                } else {
                    if (ok) yout[(size_t)tok * N_TOT + col] = v;
                }
            }
        }
    }
}

// ===================== fp32-W fallback (R3 path, used if ws too small) =========
template<int K_TOT, int N_TOT, bool IS_FFN1>
__global__ __launch_bounds__(256, 2) void ffn_gemm_f32(
    const __hip_bfloat16* __restrict__ A,
    const float* __restrict__ W,
    const float* __restrict__ bias,
    const int* __restrict__ counts,
    const int* __restrict__ bucket,
    __hip_bfloat16* __restrict__ hout,
    float* __restrict__ yout)
{
    const int e   = blockIdx.z;
    const int cnt = counts[e];
    const int m0  = blockIdx.y * 128;
    if (m0 >= cnt) return;
    const int n0   = blockIdx.x * 128;
    const int tid  = threadIdx.x;
    const int lane = tid & 63;
    const int wid  = tid >> 6;
    const int wm   = wid >> 1, wn = wid & 1;

    __shared__ __hip_bfloat16 As[128 * 64];
    __shared__ __hip_bfloat16 Bs[128 * 64];
    __shared__ int s_tok[128];

    if (tid < 128) {
        int idx = m0 + tid;
        if (idx >= cnt) idx = cnt - 1;
        s_tok[tid] = bucket[e * N_TOK + idx];
    }
    __syncthreads();

    const __hip_bfloat16* gA[4]; char* lA[4];
#pragma unroll
    for (int i = 0; i < 4; ++i) {
        const int r = wid * 32 + i * 8 + (lane >> 3);
        gA[i] = A + (size_t)s_tok[r] * K_TOT + (((lane & 7) ^ (r & 7)) << 3);
        lA[i] = (char*)As + (size_t)(wid * 32 + i * 8) * 128;
    }
    const int ko_t = lane & 7;
    const int nq   = wid * 8 + (lane >> 3);
    const float* wb = W + (size_t)e * K_TOT * N_TOT + (size_t)(ko_t * 8) * N_TOT + n0 + nq * 4;

    f32x4_t acc[4][4];
#pragma unroll
    for (int f = 0; f < 4; ++f)
#pragma unroll
        for (int g = 0; g < 4; ++g) acc[f][g] = (f32x4_t){0.f, 0.f, 0.f, 0.f};

    for (int k0 = 0; k0 < K_TOT; k0 += 64) {
#pragma unroll
        for (int i = 0; i < 4; ++i) gload16(gA[i] + k0, lA[i]);
        const float* wk = wb + (size_t)k0 * N_TOT;
        float4 v[8];
#pragma unroll
        for (int j = 0; j < 8; ++j) v[j] = *(const float4*)(wk + (size_t)j * N_TOT);
#pragma unroll
        for (int i = 0; i < 4; ++i) {
            const int n = nq * 4 + i;
            union { __hip_bfloat16 hh[8]; uint4 u; } pk;
#pragma unroll
            for (int j = 0; j < 8; ++j) pk.hh[j] = __float2bfloat16(((const float*)&v[j])[i]);
            *(uint4*)((char*)Bs + n * 128 + ((ko_t ^ (n & 7)) << 4)) = pk.u;
        }
        __syncthreads();

#pragma unroll
        for (int kk = 0; kk < 2; ++kk) {
            uint4 af[4], bf[4];
            const int ko = kk * 4 + (lane >> 4);
#pragma unroll
            for (int f = 0; f < 4; ++f) {
                const int r = wm * 64 + f * 16 + (lane & 15);
                af[f] = *(const uint4*)((const char*)As + r * 128 + ((ko ^ (r & 7)) << 4));
            }
#pragma unroll
            for (int g = 0; g < 4; ++g) {
                const int n = wn * 64 + g * 16 + (lane & 15);
                bf[g] = *(const uint4*)((const char*)Bs + n * 128 + ((ko ^ (n & 7)) << 4));
            }
#pragma unroll
            for (int f = 0; f < 4; ++f)
#pragma unroll
                for (int g = 0; g < 4; ++g)
                    acc[f][g] = __builtin_amdgcn_mfma_f32_16x16x32_bf16(
                        __builtin_bit_cast(bf16x8_t, af[f]),
                        __builtin_bit_cast(bf16x8_t, bf[g]),
                        acc[f][g], 0, 0, 0);
        }
        __syncthreads();
    }

#pragma unroll
    for (int f = 0; f < 4; ++f) {
#pragma unroll
        for (int j = 0; j < 4; ++j) {
            const int rl = wm * 64 + f * 16 + (lane >> 4) * 4 + j;
            const bool ok = (m0 + rl) < cnt;
            const int tok = s_tok[rl];
#pragma unroll
            for (int g = 0; g < 4; ++g) {
                const int col = n0 + wn * 64 + g * 16 + (lane & 15);
                float v = acc[f][g][j] + bias[e * N_TOT + col];
                if (IS_FFN1) {
                    v = 0.5f * v * (1.0f + erff(v * 0.70710678118654752f));
                    if (ok) hout[(size_t)tok * N_TOT + col] = __float2bfloat16(v);
                } else {
                    if (ok) yout[(size_t)tok * N_TOT + col] = v;
                }
            }
        }
    }
}

extern "C" void kernel_launch(void* const* d_in, const int* in_sizes, int n_in,
                              void* d_out, int out_size, void* d_ws, size_t ws_size,
                              hipStream_t stream) {
    const float* x  = (const float*)d_in[0];
    const float* Wg = (const float*)d_in[1];
    const float* bg = (const float*)d_in[2];
    const float* W1 = (const float*)d_in[3];
    const float* b1 = (const float*)d_in[4];
    const float* W2 = (const float*)d_in[5];
    const float* b2 = (const float*)d_in[6];
    float* out = (float*)d_out;

    char* ws = (char*)d_ws;
    int* counts = (int*)(ws);
    int* bucket = (int*)(ws + WS_BUCKET_OFF);
    __hip_bfloat16* xb  = (__hip_bfloat16*)(ws + WS_XB_OFF);
    __hip_bfloat16* h   = (__hip_bfloat16*)(ws + WS_H_OFF);
    __hip_bfloat16* w1b = (__hip_bfloat16*)(ws + WS_W1B_OFF);
    __hip_bfloat16* w2b = (__hip_bfloat16*)(ws + WS_W2B_OFF);

    init_counts<<<dim3(1), dim3(64), 0, stream>>>(counts);
    router_kernel<<<dim3(N_TOK / 4), dim3(256), 0, stream>>>(x, Wg, bg, counts, bucket, xb);

    if (ws_size >= WS_NEED) {
        // pre-convert W1, W2 to bf16 [e][n][k]
        convert_w<D_MODEL, D_HIDDEN><<<dim3(D_HIDDEN / 64, D_MODEL / 64, N_EXP), dim3(256), 0, stream>>>(W1, w1b);
        convert_w<D_HIDDEN, D_MODEL><<<dim3(D_MODEL / 64, D_HIDDEN / 64, N_EXP), dim3(256), 0, stream>>>(W2, w2b);
        // FFN1: M<=4096/e, N=4096, K=1024, BN=128
        ffn_gemm_bf16<D_MODEL, D_HIDDEN, 128, true>
            <<<dim3(D_HIDDEN / 128, N_TOK / 128, N_EXP), dim3(256), 0, stream>>>(
                xb, w1b, b1, counts, bucket, h, nullptr);
        // FFN2: N=1024, K=4096, BN=64 (512+ active blocks -> 2/CU)
        ffn_gemm_bf16<D_HIDDEN, D_MODEL, 64, false>
            <<<dim3(D_MODEL / 64, N_TOK / 128, N_EXP), dim3(256), 0, stream>>>(
                h, w2b, b2, counts, bucket, nullptr, out);
    } else {
        ffn_gemm_f32<D_MODEL, D_HIDDEN, true>
            <<<dim3(D_HIDDEN / 128, N_TOK / 128, N_EXP), dim3(256), 0, stream>>>(
                xb, W1, b1, counts, bucket, h, nullptr);
        ffn_gemm_f32<D_HIDDEN, D_MODEL, false>
            <<<dim3(D_MODEL / 128, N_TOK / 128, N_EXP), dim3(256), 0, stream>>>(
                h, W2, b2, counts, bucket, nullptr, out);
    }
}